// Round 1
// baseline (292.123 us; speedup 1.0000x reference)
//
#include <hip/hip_runtime.h>
#include <stdint.h>

// SelfAttention: B=4 S=4096 d_model=1024 d_out=64, fp32 in/out.
// Pipeline: prep (W->bf16^T, fold log2e/8 into Wq,bq) -> proj (bf16 MFMA GEMM,
// q/k row-major bf16, v transposed) -> flash attention (bf16 MFMA, fp32 accum).

typedef __attribute__((ext_vector_type(8))) short bf16x8;
typedef __attribute__((ext_vector_type(4))) float f32x4;

#define LOG2E_OVER8 0.1803368801111204f

__device__ __forceinline__ unsigned short f2bf(float f) {
  union { float f; uint32_t u; } v; v.f = f;
  return (unsigned short)((v.u + 0x7FFFu + ((v.u >> 16) & 1u)) >> 16);
}
__device__ __forceinline__ uint32_t f2bf2(float a, float b) {
  return (uint32_t)f2bf(a) | ((uint32_t)f2bf(b) << 16);
}

// ---------------- prep: W (1024x64 f32) -> wt[3][64][1024] bf16 (transposed), bias f32 ----
__global__ void prep_kernel(const float* __restrict__ Wq, const float* __restrict__ bq,
                            const float* __restrict__ Wk, const float* __restrict__ bk,
                            const float* __restrict__ Wv, const float* __restrict__ bv,
                            unsigned short* __restrict__ wt, float* __restrict__ bias) {
  int idx = blockIdx.x * 256 + threadIdx.x;      // 0..196607
  int p = idx >> 16;
  int rem = idx & 65535;                          // = k*64 + col
  int k = rem >> 6, col = rem & 63;
  const float* W = p == 0 ? Wq : (p == 1 ? Wk : Wv);
  float scale = (p == 0) ? LOG2E_OVER8 : 1.0f;
  wt[(p << 16) + col * 1024 + k] = f2bf(W[rem] * scale);
  if (idx < 192) {
    int pp = idx >> 6, cc = idx & 63;
    const float* bsrc = pp == 0 ? bq : (pp == 1 ? bk : bv);
    bias[idx] = bsrc[cc] * ((pp == 0) ? LOG2E_OVER8 : 1.0f);
  }
}

// ---------------- proj: X[16384,1024] @ W[1024,64] + b -> bf16 --------------------------
// p=0 -> q (scaled, row-major), p=1 -> k (row-major), p=2 -> v TRANSPOSED [B][64][S]
__global__ __launch_bounds__(256, 2)
void proj_kernel(const float* __restrict__ Xq, const float* __restrict__ Xk,
                 const float* __restrict__ Xv,
                 const unsigned short* __restrict__ wt, const float* __restrict__ bias,
                 unsigned short* __restrict__ qo, unsigned short* __restrict__ ko,
                 unsigned short* __restrict__ vo) {
  __shared__ uint32_t Xs[128][36];   // 128 rows x 72 bf16 (pad +8)
  __shared__ uint32_t Ws[64][36];    // 64 cols  x 72 bf16 (W^T chunk)
  const int p = blockIdx.y;
  const float* X = p == 0 ? Xq : (p == 1 ? Xk : Xv);
  const int row0 = blockIdx.x * 128;
  const int tid = threadIdx.x;
  const int wv = tid >> 6, lane = tid & 63, c = lane & 15, G = lane >> 4;
  const int srow = tid >> 1, shalf = tid & 1;   // X staging: 2 threads/row, 32 floats each
  const int wcol = tid >> 2, wq = tid & 3;      // W staging: 4 threads/col, 16 bf16 each

  f32x4 acc[2][4] = {};

  for (int kk = 0; kk < 1024; kk += 64) {
    { // stage X chunk [128][64] f32 -> bf16 LDS
      const float4* src = (const float4*)(X + (size_t)(row0 + srow) * 1024 + kk + shalf * 32);
      uint32_t pk[16];
#pragma unroll
      for (int i = 0; i < 8; i++) {
        float4 f = src[i];
        pk[2 * i]     = f2bf2(f.x, f.y);
        pk[2 * i + 1] = f2bf2(f.z, f.w);
      }
      uint4* dst = (uint4*)&Xs[srow][shalf * 16];
#pragma unroll
      for (int i = 0; i < 4; i++) dst[i] = ((const uint4*)pk)[i];
    }
    { // stage W^T chunk [64 cols][64 k] bf16 (already transposed in ws)
      const uint4* src = (const uint4*)(wt + (p << 16) + wcol * 1024 + kk + wq * 16);
      uint4* dst = (uint4*)&Ws[wcol][wq * 8];
      dst[0] = src[0]; dst[1] = src[1];
    }
    __syncthreads();
#pragma unroll
    for (int k2 = 0; k2 < 2; k2++) {
      bf16x8 a0 = *(const bf16x8*)((const char*)&Xs[wv * 32 + c][0]      + k2 * 64 + G * 16);
      bf16x8 a1 = *(const bf16x8*)((const char*)&Xs[wv * 32 + 16 + c][0] + k2 * 64 + G * 16);
#pragma unroll
      for (int n = 0; n < 4; n++) {
        bf16x8 bw = *(const bf16x8*)((const char*)&Ws[16 * n + c][0] + k2 * 64 + G * 16);
        acc[0][n] = __builtin_amdgcn_mfma_f32_16x16x32_bf16(a0, bw, acc[0][n], 0, 0, 0);
        acc[1][n] = __builtin_amdgcn_mfma_f32_16x16x32_bf16(a1, bw, acc[1][n], 0, 0, 0);
      }
    }
    __syncthreads();
  }
  float bcol[4];
#pragma unroll
  for (int n = 0; n < 4; n++) bcol[n] = bias[p * 64 + 16 * n + c];
  if (p < 2) {
    unsigned short* out = (p == 0) ? qo : ko;
#pragma unroll
    for (int a = 0; a < 2; a++)
#pragma unroll
      for (int n = 0; n < 4; n++)
#pragma unroll
        for (int r = 0; r < 4; r++) {
          int row = row0 + wv * 32 + a * 16 + G * 4 + r;
          out[(size_t)row * 64 + 16 * n + c] = f2bf(acc[a][n][r] + bcol[n]);
        }
  } else {
#pragma unroll
    for (int a = 0; a < 2; a++)
#pragma unroll
      for (int n = 0; n < 4; n++)
#pragma unroll
        for (int r = 0; r < 4; r++) {
          int row = row0 + wv * 32 + a * 16 + G * 4 + r;   // global s index
          int bb = row >> 12, sl = row & 4095;
          int e = 16 * n + c;
          vo[((size_t)(bb * 64 + e) << 12) + sl] = f2bf(acc[a][n][r] + bcol[n]);
        }
  }
}

// ---------------- flash attention ------------------------------------------------------
// grid (64,4): x=q-tile (64 rows), y=batch. 8 waves: wave w & w+4 share 16 q-rows,
// split KV range in halves (2048 keys each); merged at the end via LDS.
__global__ __launch_bounds__(512, 1)
void attn_kernel(const unsigned short* __restrict__ q_ws, const unsigned short* __restrict__ k_ws,
                 const unsigned short* __restrict__ vt_ws, float* __restrict__ out) {
  __shared__ uint32_t Ks[2][64][36];   // [group][key][d]  72-bf16 rows (pad +8)
  __shared__ uint32_t Vs[2][64][36];   // [group][d][key]
  __shared__ uint32_t Pl[8][16][36];   // per-wave P tile [q][key]
  const int b = blockIdx.y;
  const int tid = threadIdx.x;
  const int wv = tid >> 6, lane = tid & 63, c = lane & 15, G = lane >> 4;
  const int g = wv >> 2, ws_ = wv & 3;
  const int qrow = blockIdx.x * 64 + ws_ * 16;   // within S

  bf16x8 aq[2];
#pragma unroll
  for (int k2 = 0; k2 < 2; k2++)
    aq[k2] = *(const bf16x8*)(q_ws + ((size_t)(b * 4096 + qrow + c) << 6) + k2 * 32 + G * 8);

  f32x4 o[4] = {};
  float mr[4] = {-1e30f, -1e30f, -1e30f, -1e30f};
  float lp[4] = {};

  const int gb = tid >> 8, rr = (tid >> 2) & 63, cc = tid & 3;   // staging coords

  for (int t = 0; t < 32; t++) {
    { // stage K tile + V^T tile for both groups (each: 64x64 bf16)
      int kv0s = gb * 2048 + t * 64;
      const uint4* ksrc = (const uint4*)(k_ws + ((size_t)(b * 4096 + kv0s + rr) << 6) + cc * 16);
      uint4* kdst = (uint4*)&Ks[gb][rr][cc * 8];
      kdst[0] = ksrc[0]; kdst[1] = ksrc[1];
      const uint4* vsrc = (const uint4*)(vt_ws + ((size_t)(b * 64 + rr) << 12) + kv0s + cc * 16);
      uint4* vdst = (uint4*)&Vs[gb][rr][cc * 8];
      vdst[0] = vsrc[0]; vdst[1] = vsrc[1];
    }
    __syncthreads();

    // scores = q . k  (q pre-scaled by log2e/8 -> exp2 domain)
    f32x4 sc[4] = {};
#pragma unroll
    for (int k2 = 0; k2 < 2; k2++)
#pragma unroll
      for (int f = 0; f < 4; f++) {
        bf16x8 bk = *(const bf16x8*)((const char*)&Ks[g][16 * f + c][0] + k2 * 64 + G * 16);
        sc[f] = __builtin_amdgcn_mfma_f32_16x16x32_bf16(aq[k2], bk, sc[f], 0, 0, 0);
      }

    // online softmax; row r lives in the 16 lanes sharing G
    float mn[4];
#pragma unroll
    for (int r = 0; r < 4; r++)
      mn[r] = fmaxf(fmaxf(sc[0][r], sc[1][r]), fmaxf(sc[2][r], sc[3][r]));
#pragma unroll
    for (int msk = 1; msk <= 8; msk <<= 1)
#pragma unroll
      for (int r = 0; r < 4; r++)
        mn[r] = fmaxf(mn[r], __shfl_xor(mn[r], msk));

    float pv[4][4];
#pragma unroll
    for (int r = 0; r < 4; r++) {
      float M = fmaxf(mr[r], mn[r]);
      float al = __builtin_amdgcn_exp2f(mr[r] - M);
      mr[r] = M;
      lp[r] *= al;
#pragma unroll
      for (int df = 0; df < 4; df++) o[df][r] *= al;
#pragma unroll
      for (int f = 0; f < 4; f++) pv[f][r] = __builtin_amdgcn_exp2f(sc[f][r] - M);
      lp[r] += (pv[0][r] + pv[1][r]) + (pv[2][r] + pv[3][r]);
    }

    // P -> bf16 via per-wave LDS tile (D-frag layout -> A-frag layout)
    unsigned short* plw = (unsigned short*)&Pl[wv][0][0];
#pragma unroll
    for (int f = 0; f < 4; f++)
#pragma unroll
      for (int r = 0; r < 4; r++)
        plw[(4 * G + r) * 72 + 16 * f + c] = f2bf(pv[f][r]);

    bf16x8 pa[2];
    pa[0] = *(const bf16x8*)((const char*)&Pl[wv][0][0] + c * 144 + G * 16);
    pa[1] = *(const bf16x8*)((const char*)&Pl[wv][0][0] + c * 144 + 64 + G * 16);
#pragma unroll
    for (int k2 = 0; k2 < 2; k2++)
#pragma unroll
      for (int df = 0; df < 4; df++) {
        bf16x8 bvv = *(const bf16x8*)((const char*)&Vs[g][16 * df + c][0] + k2 * 64 + G * 16);
        o[df] = __builtin_amdgcn_mfma_f32_16x16x32_bf16(pa[k2], bvv, o[df], 0, 0, 0);
      }
    __syncthreads();
  }

  // finish l reduction across the 16-lane row group
#pragma unroll
  for (int msk = 1; msk <= 8; msk <<= 1)
#pragma unroll
    for (int r = 0; r < 4; r++) lp[r] += __shfl_xor(lp[r], msk);

  // merge the two KV-half partials (reuse Ks/Vs LDS)
  float* Osh = (float*)&Ks[0][0][0];   // [4][16][65] f32
  float* msh = (float*)&Vs[0][0][0];   // [4*16]
  float* lsh = msh + 64;
  if (g == 1) {
#pragma unroll
    for (int df = 0; df < 4; df++)
#pragma unroll
      for (int r = 0; r < 4; r++)
        Osh[(ws_ * 16 + 4 * G + r) * 65 + 16 * df + c] = o[df][r];
    if (c == 0) {
#pragma unroll
      for (int r = 0; r < 4; r++) {
        msh[ws_ * 16 + 4 * G + r] = mr[r];
        lsh[ws_ * 16 + 4 * G + r] = lp[r];
      }
    }
  }
  __syncthreads();
  if (g == 0) {
#pragma unroll
    for (int r = 0; r < 4; r++) {
      int rowi = ws_ * 16 + 4 * G + r;
      float m1 = msh[rowi], l1 = lsh[rowi];
      float M = fmaxf(mr[r], m1);
      float a0 = __builtin_amdgcn_exp2f(mr[r] - M);
      float a1 = __builtin_amdgcn_exp2f(m1 - M);
      float inv = 1.0f / (a0 * lp[r] + a1 * l1);
#pragma unroll
      for (int df = 0; df < 4; df++) {
        float val = (a0 * o[df][r] + a1 * Osh[rowi * 65 + 16 * df + c]) * inv;
        out[((size_t)(b * 4096 + blockIdx.x * 64 + rowi) << 6) + 16 * df + c] = val;
      }
    }
  }
}

// ---------------- launch ---------------------------------------------------------------
extern "C" void kernel_launch(void* const* d_in, const int* in_sizes, int n_in,
                              void* d_out, int out_size, void* d_ws, size_t ws_size,
                              hipStream_t stream) {
  const float* query = (const float*)d_in[0];
  const float* key   = (const float*)d_in[1];
  const float* value = (const float*)d_in[2];
  const float* Wq = (const float*)d_in[3];
  const float* bq = (const float*)d_in[4];
  const float* Wk = (const float*)d_in[5];
  const float* bk = (const float*)d_in[6];
  const float* Wv = (const float*)d_in[7];
  const float* bv = (const float*)d_in[8];

  char* ws = (char*)d_ws;
  unsigned short* q_ws  = (unsigned short*)(ws);                    // [4][4096][64] bf16, pre-scaled
  unsigned short* k_ws  = (unsigned short*)(ws + (2u << 20));       // [4][4096][64] bf16
  unsigned short* vt_ws = (unsigned short*)(ws + (4u << 20));       // [4][64][4096] bf16 (transposed)
  unsigned short* wt_ws = (unsigned short*)(ws + (6u << 20));       // [3][64][1024] bf16
  float* bias_ws        = (float*)(ws + (6u << 20) + 393216);       // [3][64] f32

  prep_kernel<<<768, 256, 0, stream>>>(Wq, bq, Wk, bk, Wv, bv, wt_ws, bias_ws);
  proj_kernel<<<dim3(128, 3), 256, 0, stream>>>(query, key, value, wt_ws, bias_ws,
                                                q_ws, k_ws, vt_ws);
  attn_kernel<<<dim3(64, 4), 512, 0, stream>>>(q_ws, k_ws, vt_ws, (float*)d_out);
}

// Round 4
// 286.338 us; speedup vs baseline: 1.0202x; 1.0202x over previous
//
#include <hip/hip_runtime.h>
#include <stdint.h>

// SelfAttention: B=4 S=4096 d_model=1024 d_out=64, fp32 in/out.
// prep (W->bf16^T swizz-ready, fold log2e/8 into Wq,bq)
// proj (global_load_lds + XOR-swizzle, 2-phase dbuf, bf16 MFMA) -> q,k row-major bf16, v^T
// attn (flash, 512 blocks XCD-swizzled, global_load_lds K/V, 2-phase dbuf)

typedef __attribute__((ext_vector_type(8))) short bf16x8;
typedef __attribute__((ext_vector_type(4))) float f32x4;

#define LOG2E_OVER8 0.1803368801111204f

#define GLOAD16(gptr, lptr)                                                            \
  __builtin_amdgcn_global_load_lds((const __attribute__((address_space(1))) uint32_t*)(gptr), \
                                   (__attribute__((address_space(3))) uint32_t*)(lptr), 16, 0, 0)

__device__ __forceinline__ unsigned short f2bf(float f) {
  union { float f; uint32_t u; } v; v.f = f;
  return (unsigned short)((v.u + 0x7FFFu + ((v.u >> 16) & 1u)) >> 16);
}
__device__ __forceinline__ uint32_t f2bf2(float a, float b) {
  return (uint32_t)f2bf(a) | ((uint32_t)f2bf(b) << 16);
}
__device__ __forceinline__ unsigned short f2bf_fast(float f) {  // round-half-up (P values only)
  union { float f; uint32_t u; } v; v.f = f;
  return (unsigned short)((v.u + 0x8000u) >> 16);
}

// ---------------- prep: W (1024x64 f32) -> wt[3][64][1024] bf16 (transposed), bias f32 ----
__global__ void prep_kernel(const float* __restrict__ Wq, const float* __restrict__ bq,
                            const float* __restrict__ Wk, const float* __restrict__ bk,
                            const float* __restrict__ Wv, const float* __restrict__ bv,
                            unsigned short* __restrict__ wt, float* __restrict__ bias) {
  int idx = blockIdx.x * 256 + threadIdx.x;      // 0..196607
  int p = idx >> 16;
  int rem = idx & 65535;                          // = k*64 + col
  int k = rem >> 6, col = rem & 63;
  const float* W = p == 0 ? Wq : (p == 1 ? Wk : Wv);
  float scale = (p == 0) ? LOG2E_OVER8 : 1.0f;
  wt[(p << 16) + col * 1024 + k] = f2bf(W[rem] * scale);
  if (idx < 192) {
    int pp = idx >> 6, cc = idx & 63;
    const float* bsrc = pp == 0 ? bq : (pp == 1 ? bk : bv);
    bias[idx] = bsrc[cc] * ((pp == 0) ? LOG2E_OVER8 : 1.0f);
  }
}

// ---------------- proj: X[16384,1024] @ W[1024,64] + b -> bf16 --------------------------
// BM=64, BK=64, 4 waves (16 rows each). X staged f32 via global_load_lds (XOR-swizzled
// source, linear LDS, swizzled read), W bf16 likewise. 2-phase double buffer.
__global__ __launch_bounds__(256)
void proj_kernel(const float* __restrict__ Xq, const float* __restrict__ Xk,
                 const float* __restrict__ Xv,
                 const unsigned short* __restrict__ wt, const float* __restrict__ bias,
                 unsigned short* __restrict__ qo, unsigned short* __restrict__ ko,
                 unsigned short* __restrict__ vo) {
  __shared__ float Xs[2][64][64];            // 32 KB (linear, source pre-swizzled)
  __shared__ unsigned short Wsh[2][64][64];  // 16 KB
  const int p = blockIdx.y;
  const float* X = p == 0 ? Xq : (p == 1 ? Xk : Xv);
  const int row0 = blockIdx.x * 64;
  const int tid = threadIdx.x;
  const int lane = tid & 63, wv = tid >> 6, c = lane & 15, G = lane >> 4;
  const int wvoff = wv * 1024;               // per-wave LDS byte offset within a 4KB call

  // X staging: call s covers rows s*16..s*16+15. chunk = s*256 + tid.
  const int xsrow = tid >> 4;                        // 0..15 (row within segment)
  const int xcol = ((tid & 15) ^ xsrow) * 4;         // pre-swizzled logical col (floats)
  // W staging: call s2 covers cols s2*32..+31. chunk = s2*256 + tid.
  const int wcolr = tid >> 3;                        // 0..31
  const int wkoff = ((tid & 7) ^ (wcolr & 7)) * 8;   // pre-swizzled k-offset (elems)

  f32x4 acc[4] = {};

  auto STAGE = [&](int bufi, int kk) {
    char* xb = (char*)&Xs[bufi][0][0];
    char* wb = (char*)&Wsh[bufi][0][0];
#pragma unroll
    for (int s = 0; s < 4; s++) {
      const float* src = X + (size_t)(row0 + s * 16 + xsrow) * 1024 + kk + xcol;
      GLOAD16(src, xb + s * 4096 + wvoff);
    }
#pragma unroll
    for (int s2 = 0; s2 < 2; s2++) {
      const unsigned short* src = wt + (p << 16) + (size_t)(s2 * 32 + wcolr) * 1024 + kk + wkoff;
      GLOAD16(src, wb + s2 * 4096 + wvoff);
    }
  };

  STAGE(0, 0);
  __syncthreads();
  int buf = 0;
  for (int kk = 0; kk < 1024; kk += 64) {
    if (kk < 960) STAGE(buf ^ 1, kk + 64);
    const char* xb = (const char*)&Xs[buf][0][0];
    const char* wb = (const char*)&Wsh[buf][0][0];
#pragma unroll
    for (int k2 = 0; k2 < 2; k2++) {
      float4 f0 = *(const float4*)(xb + (wv * 16 + c) * 256 + ((k2 * 8 + G * 2) ^ c) * 16);
      float4 f1 = *(const float4*)(xb + (wv * 16 + c) * 256 + ((k2 * 8 + G * 2 + 1) ^ c) * 16);
      union { uint32_t u[4]; bf16x8 v; } cv;
      cv.u[0] = f2bf2(f0.x, f0.y); cv.u[1] = f2bf2(f0.z, f0.w);
      cv.u[2] = f2bf2(f1.x, f1.y); cv.u[3] = f2bf2(f1.z, f1.w);
      bf16x8 a = cv.v;
#pragma unroll
      for (int n = 0; n < 4; n++) {
        bf16x8 bw = *(const bf16x8*)(wb + (16 * n + c) * 128 + (((k2 * 4 + G) ^ (c & 7)) * 16));
        acc[n] = __builtin_amdgcn_mfma_f32_16x16x32_bf16(a, bw, acc[n], 0, 0, 0);
      }
    }
    __syncthreads();
    buf ^= 1;
  }

  float bcol[4];
#pragma unroll
  for (int n = 0; n < 4; n++) bcol[n] = bias[p * 64 + 16 * n + c];
  if (p < 2) {
    unsigned short* out = (p == 0) ? qo : ko;
#pragma unroll
    for (int n = 0; n < 4; n++)
#pragma unroll
      for (int r = 0; r < 4; r++) {
        int row = row0 + wv * 16 + G * 4 + r;
        out[(size_t)row * 64 + 16 * n + c] = f2bf(acc[n][r] + bcol[n]);
      }
  } else {
#pragma unroll
    for (int n = 0; n < 4; n++)
#pragma unroll
      for (int r = 0; r < 4; r++) {
        int row = row0 + wv * 16 + G * 4 + r;   // global s index
        int bb = row >> 12, sl = row & 4095;
        int e = 16 * n + c;
        vo[((size_t)(bb * 64 + e) << 12) + sl] = f2bf(acc[n][r] + bcol[n]);
      }
  }
}

// ---------------- flash attention ------------------------------------------------------
// 512 blocks (XCD-remapped: each XCD sees one batch), 4 waves: ws_=q-strip(16 rows),
// g=KV half (2048 keys). K/V staged via global_load_lds (XOR-swizzled source),
// double-buffered, one barrier per KV tile.
__global__ __launch_bounds__(256)
void attn_kernel(const unsigned short* __restrict__ q_ws, const unsigned short* __restrict__ k_ws,
                 const unsigned short* __restrict__ vt_ws, float* __restrict__ out) {
  __shared__ unsigned short Ks[2][2][64][64];  // [buf][group][key][d] 32 KB
  __shared__ unsigned short Vs[2][2][64][64];  // [buf][group][d][key] 32 KB
  __shared__ uint32_t Pl[4][16][36];           // per-wave P tile (padded)
  __shared__ float msh[2][16], lsh[2][16];
  const int bid = blockIdx.x;
  const int b = (bid & 7) >> 1;                       // batch -> XCD pair
  const int xt = ((bid >> 3) << 1) | (bid & 1);       // q-tile 0..127
  const int tid = threadIdx.x;
  const int lane = tid & 63, wv = tid >> 6, c = lane & 15, G = lane >> 4;
  const int ws_ = wv & 1, g = wv >> 1;
  const int qrow = xt * 32 + ws_ * 16;
  const int wvoff = wv * 1024;

  // staging coords: call h covers rows h*32..+31; chunk = h*256 + tid
  const int srow = tid >> 3;                          // 0..31
  const int scol = ((tid & 7) ^ (srow & 7)) * 8;      // pre-swizzled elem offset

  bf16x8 aq[2];
#pragma unroll
  for (int k2 = 0; k2 < 2; k2++)
    aq[k2] = *(const bf16x8*)(q_ws + ((size_t)(b * 4096 + qrow + c) << 6) + k2 * 32 + G * 8);

  f32x4 o[4] = {};
  float mr[4] = {-1e30f, -1e30f, -1e30f, -1e30f};
  float lp[4] = {};

  auto STAGE = [&](int bufi, int t) {
#pragma unroll
    for (int gb = 0; gb < 2; gb++) {
      int kv0 = gb * 2048 + t * 64;
      char* kb = (char*)&Ks[bufi][gb][0][0];
      char* vb = (char*)&Vs[bufi][gb][0][0];
#pragma unroll
      for (int h = 0; h < 2; h++) {
        const unsigned short* ksrc = k_ws + ((size_t)(b * 4096 + kv0 + h * 32 + srow) << 6) + scol;
        GLOAD16(ksrc, kb + h * 4096 + wvoff);
        const unsigned short* vsrc = vt_ws + ((size_t)(b * 64 + h * 32 + srow) << 12) + kv0 + scol;
        GLOAD16(vsrc, vb + h * 4096 + wvoff);
      }
    }
  };

  STAGE(0, 0);
  __syncthreads();
  int buf = 0;
  for (int t = 0; t < 32; t++) {
    if (t < 31) STAGE(buf ^ 1, t + 1);
    const char* kb = (const char*)&Ks[buf][g][0][0];
    const char* vb = (const char*)&Vs[buf][g][0][0];

    // scores = q.k (exp2 domain, pre-scaled)
    f32x4 sc[4] = {};
#pragma unroll
    for (int k2 = 0; k2 < 2; k2++)
#pragma unroll
      for (int f = 0; f < 4; f++) {
        bf16x8 bk = *(const bf16x8*)(kb + (16 * f + c) * 128 + (((k2 * 4 + G) ^ (c & 7)) * 16));
        sc[f] = __builtin_amdgcn_mfma_f32_16x16x32_bf16(aq[k2], bk, sc[f], 0, 0, 0);
      }

    // online softmax (row r lives in 16 lanes sharing G)
    float mn[4];
#pragma unroll
    for (int r = 0; r < 4; r++)
      mn[r] = fmaxf(fmaxf(sc[0][r], sc[1][r]), fmaxf(sc[2][r], sc[3][r]));
#pragma unroll
    for (int msk = 1; msk <= 8; msk <<= 1)
#pragma unroll
      for (int r = 0; r < 4; r++)
        mn[r] = fmaxf(mn[r], __shfl_xor(mn[r], msk));

    float pv[4][4];
#pragma unroll
    for (int r = 0; r < 4; r++) {
      float M = fmaxf(mr[r], mn[r]);
      float al = __builtin_amdgcn_exp2f(mr[r] - M);
      mr[r] = M;
      lp[r] *= al;
#pragma unroll
      for (int df = 0; df < 4; df++) o[df][r] *= al;
#pragma unroll
      for (int f = 0; f < 4; f++) pv[f][r] = __builtin_amdgcn_exp2f(sc[f][r] - M);
      lp[r] += (pv[0][r] + pv[1][r]) + (pv[2][r] + pv[3][r]);
    }

    // P -> bf16 via per-wave LDS tile (D-frag -> A-frag relayout)
    unsigned short* plw = (unsigned short*)&Pl[wv][0][0];
#pragma unroll
    for (int f = 0; f < 4; f++)
#pragma unroll
      for (int r = 0; r < 4; r++)
        plw[(4 * G + r) * 72 + 16 * f + c] = f2bf_fast(pv[f][r]);

    bf16x8 pa[2];
    pa[0] = *(const bf16x8*)((const char*)&Pl[wv][0][0] + c * 144 + G * 16);
    pa[1] = *(const bf16x8*)((const char*)&Pl[wv][0][0] + c * 144 + 64 + G * 16);
#pragma unroll
    for (int k2 = 0; k2 < 2; k2++)
#pragma unroll
      for (int df = 0; df < 4; df++) {
        bf16x8 bvv = *(const bf16x8*)(vb + (16 * df + c) * 128 + (((k2 * 4 + G) ^ (c & 7)) * 16));
        o[df] = __builtin_amdgcn_mfma_f32_16x16x32_bf16(pa[k2], bvv, o[df], 0, 0, 0);
      }
    __syncthreads();
    buf ^= 1;
  }

  // finish l reduction across the 16-lane row group
#pragma unroll
  for (int msk = 1; msk <= 8; msk <<= 1)
#pragma unroll
    for (int r = 0; r < 4; r++) lp[r] += __shfl_xor(lp[r], msk);

  // merge the two KV-half partials (reuse Ks as f32 scratch)
  float* Osh = (float*)&Ks[0][0][0][0];   // [2][16][65]
  if (g == 1) {
#pragma unroll
    for (int df = 0; df < 4; df++)
#pragma unroll
      for (int r = 0; r < 4; r++)
        Osh[(ws_ * 16 + 4 * G + r) * 65 + 16 * df + c] = o[df][r];
    if (c == 0) {
#pragma unroll
      for (int r = 0; r < 4; r++) {
        msh[ws_][4 * G + r] = mr[r];
        lsh[ws_][4 * G + r] = lp[r];
      }
    }
  }
  __syncthreads();
  if (g == 0) {
#pragma unroll
    for (int r = 0; r < 4; r++) {
      int rowi = 4 * G + r;
      float m1 = msh[ws_][rowi], l1 = lsh[ws_][rowi];
      float M = fmaxf(mr[r], m1);
      float a0 = __builtin_amdgcn_exp2f(mr[r] - M);
      float a1 = __builtin_amdgcn_exp2f(m1 - M);
      float inv = 1.0f / (a0 * lp[r] + a1 * l1);
#pragma unroll
      for (int df = 0; df < 4; df++) {
        float val = (a0 * o[df][r] + a1 * Osh[(ws_ * 16 + rowi) * 65 + 16 * df + c]) * inv;
        out[((size_t)(b * 4096 + qrow + rowi) << 6) + 16 * df + c] = val;
      }
    }
  }
}

// ---------------- launch ---------------------------------------------------------------
extern "C" void kernel_launch(void* const* d_in, const int* in_sizes, int n_in,
                              void* d_out, int out_size, void* d_ws, size_t ws_size,
                              hipStream_t stream) {
  const float* query = (const float*)d_in[0];
  const float* key   = (const float*)d_in[1];
  const float* value = (const float*)d_in[2];
  const float* Wq = (const float*)d_in[3];
  const float* bq = (const float*)d_in[4];
  const float* Wk = (const float*)d_in[5];
  const float* bk = (const float*)d_in[6];
  const float* Wv = (const float*)d_in[7];
  const float* bv = (const float*)d_in[8];

  char* ws = (char*)d_ws;
  unsigned short* q_ws  = (unsigned short*)(ws);                    // [4][4096][64] bf16, pre-scaled
  unsigned short* k_ws  = (unsigned short*)(ws + (2u << 20));       // [4][4096][64] bf16
  unsigned short* vt_ws = (unsigned short*)(ws + (4u << 20));       // [4][64][4096] bf16 (transposed)
  unsigned short* wt_ws = (unsigned short*)(ws + (6u << 20));       // [3][64][1024] bf16
  float* bias_ws        = (float*)(ws + (6u << 20) + 393216);       // [3][64] f32

  prep_kernel<<<768, 256, 0, stream>>>(Wq, bq, Wk, bk, Wv, bv, wt_ws, bias_ws);
  proj_kernel<<<dim3(256, 3), 256, 0, stream>>>(query, key, value, wt_ws, bias_ws,
                                                q_ws, k_ws, vt_ws);
  attn_kernel<<<512, 256, 0, stream>>>(q_ws, k_ws, vt_ws, (float*)d_out);
}